// Round 9
// baseline (531.673 us; speedup 1.0000x reference)
//
#include <hip/hip_runtime.h>
#include <hip/hip_bf16.h>

// Problem constants
#define N_SERVICES 5825
#define N_FEAT     16384
#define EMB        64
#define BATCH      16384

#define MT         365                  // ceil(5825/16) M-tiles of 16 rows
#define KSTEPS     (N_FEAT / 32)        // 512 MFMA k-steps (K=32 each)
#define KSPLIT_G   8                    // grid-level split-K
#define WAVES      4                    // waves per block, each takes a K sub-chunk
#define KC_EFF     (KSPLIT_G * WAVES)   // 32 effective K-chunks
#define KSTEPS_PW  (KSTEPS / KC_EFF)    // 16 k-steps per wave

#define TILE_F     (16 * EMB)           // 1024 floats per output tile
#define PROJ_F     (MT * TILE_F)        // 373,760 floats per K-slice
#define PROJ_V4    (PROJ_F / 4)         // 93,440 float4 per K-slice

typedef __bf16 bf16x8 __attribute__((ext_vector_type(8)));
typedef float  f32x4  __attribute__((ext_vector_type(4)));
typedef unsigned short ushort_t;

__device__ __forceinline__ bf16x8 load_bfrag(const ushort_t* p) {
    uint4 v = *reinterpret_cast<const uint4*>(p);
    return __builtin_bit_cast(bf16x8, v);
}

// ---------------------------------------------------------------------------
// Repack embedding [16384][64] fp32 -> bf16 B-fragments.
//   lane l, reg j holds B[k0 + (l>>4)*8 + j][n0 + (l&15)]
// Packed address: Bp[ ((ks*4 + nt)*64 + l)*8 + j ]  (16 B contiguous per lane)
// ---------------------------------------------------------------------------
__global__ __launch_bounds__(256) void pack_b(const float* __restrict__ B,
                                              ushort_t* __restrict__ Bp) {
    int t  = blockIdx.x * 256 + threadIdx.x;   // 0 .. 512*4*64-1
    int l  = t & 63;
    int g  = t >> 6;            // ks*4 + nt
    int nt = g & 3;
    int ks = g >> 2;
    int col = nt * 16 + (l & 15);
    int kb  = ks * 32 + ((l >> 4) << 3);

    alignas(16) ushort_t u[8];
#pragma unroll
    for (int j = 0; j < 8; ++j) {
        float v = B[(size_t)(kb + j) * EMB + col];
        __bf16 h = (__bf16)v;
        u[j] = __builtin_bit_cast(ushort_t, h);
    }
    *reinterpret_cast<uint4*>(Bp + (size_t)t * 8) = *reinterpret_cast<const uint4*>(u);
}

// ---------------------------------------------------------------------------
// partial[kcg][mt tile] = A_mtile @ B over this block's K range.
// Block = 256 threads = 4 waves; wave w handles K-chunk (blockIdx.y*4 + w).
// All 4 waves compute the SAME 16x64 tile -> LDS reduce -> one coalesced
// 4 KB store per block. NO global atomics.
// ---------------------------------------------------------------------------
__global__ __launch_bounds__(256) void gemm_proj(const float* __restrict__ A,
                                                 const ushort_t* __restrict__ Bp,
                                                 float* __restrict__ partial) {
    __shared__ float lds[WAVES][TILE_F];   // 16 KB

    const int mt  = blockIdx.x;
    const int wid = threadIdx.x >> 6;
    const int l   = threadIdx.x & 63;
    const int kc  = blockIdx.y * WAVES + wid;

    int row = mt * 16 + (l & 15);
    if (row >= N_SERVICES) row = N_SERVICES - 1;   // clamp: pad rows never gathered

    const float*    Arow = A + (size_t)row * N_FEAT + ((l >> 4) << 3);
    const ushort_t* Bl   = Bp + (size_t)l * 8;

    f32x4 acc0 = {0.f, 0.f, 0.f, 0.f};
    f32x4 acc1 = {0.f, 0.f, 0.f, 0.f};
    f32x4 acc2 = {0.f, 0.f, 0.f, 0.f};
    f32x4 acc3 = {0.f, 0.f, 0.f, 0.f};

    const int ks0 = kc * KSTEPS_PW;
#pragma unroll 8
    for (int s = 0; s < KSTEPS_PW; ++s) {
        const int ks = ks0 + s;
        const float4 a0 = *reinterpret_cast<const float4*>(Arow + (size_t)ks * 32);
        const float4 a1 = *reinterpret_cast<const float4*>(Arow + (size_t)ks * 32 + 4);

        const size_t bbase = (size_t)(ks * 4) * 64 * 8;
        bf16x8 b0 = load_bfrag(Bl + bbase);
        bf16x8 b1 = load_bfrag(Bl + bbase + 1 * 64 * 8);
        bf16x8 b2 = load_bfrag(Bl + bbase + 2 * 64 * 8);
        bf16x8 b3 = load_bfrag(Bl + bbase + 3 * 64 * 8);

        bf16x8 af;
        af[0] = (__bf16)a0.x; af[1] = (__bf16)a0.y;
        af[2] = (__bf16)a0.z; af[3] = (__bf16)a0.w;
        af[4] = (__bf16)a1.x; af[5] = (__bf16)a1.y;
        af[6] = (__bf16)a1.z; af[7] = (__bf16)a1.w;

        acc0 = __builtin_amdgcn_mfma_f32_16x16x32_bf16(af, b0, acc0, 0, 0, 0);
        acc1 = __builtin_amdgcn_mfma_f32_16x16x32_bf16(af, b1, acc1, 0, 0, 0);
        acc2 = __builtin_amdgcn_mfma_f32_16x16x32_bf16(af, b2, acc2, 0, 0, 0);
        acc3 = __builtin_amdgcn_mfma_f32_16x16x32_bf16(af, b3, acc3, 0, 0, 0);
    }

    // C/D layout: col = lane&15, row_in_tile = (lane>>4)*4 + reg
    const int rbase = ((l >> 4) << 2);
    const int col   = l & 15;
#pragma unroll
    for (int r = 0; r < 4; ++r) {
        float* lp = &lds[wid][(rbase + r) * EMB + col];
        lp[0]  = acc0[r];
        lp[16] = acc1[r];
        lp[32] = acc2[r];
        lp[48] = acc3[r];
    }
    __syncthreads();

    // Reduce 4 waves -> one tile; 256 threads x float4 = 1024 floats
    const int t4 = threadIdx.x * 4;
    f32x4 s = *reinterpret_cast<const f32x4*>(&lds[0][t4]);
#pragma unroll
    for (int g = 1; g < WAVES; ++g)
        s += *reinterpret_cast<const f32x4*>(&lds[g][t4]);

    f32x4* out = reinterpret_cast<f32x4*>(partial) +
                 (size_t)blockIdx.y * PROJ_V4 + mt * (TILE_F / 4) + threadIdx.x;
    *out = s;
}

// ---------------------------------------------------------------------------
// out[b][:] = sum over 8 K-slices of partial[g][data[b]][:]
// (fused reduce + gather; partial is L2/L3-resident, 12 MB)
// Note: partial slice layout is linear in service row: row s lives at
// float offset s*64 within each slice.
// ---------------------------------------------------------------------------
__global__ __launch_bounds__(256) void reduce_gather(const int* __restrict__ data,
                                                     const f32x4* __restrict__ partial,
                                                     f32x4* __restrict__ out4) {
    int t = blockIdx.x * 256 + threadIdx.x;  // 0 .. BATCH*16-1
    int b = t >> 4;                          // batch index
    int c = t & 15;                          // float4 column
    int s = data[b];
    size_t off = (size_t)s * 16 + c;

    f32x4 acc = partial[off];
#pragma unroll
    for (int g = 1; g < KSPLIT_G; ++g)
        acc += partial[(size_t)g * PROJ_V4 + off];
    out4[t] = acc;
}

extern "C" void kernel_launch(void* const* d_in, const int* in_sizes, int n_in,
                              void* d_out, int out_size, void* d_ws, size_t ws_size,
                              hipStream_t stream) {
    const int*   data = (const int*)d_in[0];
    const float* A    = (const float*)d_in[1];   // service_matrix [5825][16384]
    const float* B    = (const float*)d_in[2];   // embedding      [16384][64]
    float*       out  = (float*)d_out;

    // workspace layout (16B aligned):
    //   Bp      [2 MiB] bf16 frags       @ 0
    //   partial [8][373760] f32 (12 MB)  @ 2,097,152
    ushort_t* Bp      = (ushort_t*)d_ws;
    float*    partial = (float*)((char*)d_ws + 2097152);

    pack_b<<<512, 256, 0, stream>>>(B, Bp);
    gemm_proj<<<dim3(MT, KSPLIT_G), 256, 0, stream>>>(A, Bp, partial);
    reduce_gather<<<(BATCH * 16) / 256, 256, 0, stream>>>(data, (const f32x4*)partial,
                                                          (f32x4*)out);
}